// Round 16
// baseline (357.734 us; speedup 1.0000x reference)
//
#include <hip/hip_runtime.h>

#define N_NODES 50000
#define N_EDGES 800000
#define CH 256
#define NUM_GRAPHS 512
#define LEAKY 0.01f
#define LN_EPS 1e-5f
#define NBLK ((N_NODES + 255) / 256)   // 196

typedef __attribute__((ext_vector_type(4))) float f32x4;
typedef __attribute__((ext_vector_type(2))) float f32x2;
typedef __attribute__((ext_vector_type(8))) short bf16x8;

__device__ __forceinline__ float b2f(unsigned short u) {
    union { unsigned int i; float f; } x; x.i = ((unsigned int)u) << 16; return x.f;
}
__device__ __forceinline__ unsigned short f2b(float f) {  // round-to-nearest-even
    union { float f; unsigned int i; } x; x.f = f;
    unsigned int r = x.i + 0x7fffu + ((x.i >> 16) & 1u);
    return (unsigned short)(r >> 16);
}
__device__ __forceinline__ f32x2 b2f2(unsigned int u) {
    union { unsigned int i; float f; } lo, hi;
    lo.i = u << 16; hi.i = u & 0xffff0000u;
    f32x2 r; r.x = lo.f; r.y = hi.f; return r;
}
__device__ __forceinline__ unsigned int pack2(float a, float b) {
    return (unsigned int)f2b(a) | ((unsigned int)f2b(b) << 16);
}

// merged: zero cnt (blocks [0,NBLK)) + W1/W2 transpose-cast (blocks [NBLK, NBLK+512))
__global__ void prep(int* __restrict__ cnt,
                     const float* __restrict__ W1f, const float* __restrict__ W2f,
                     unsigned short* __restrict__ WT1, unsigned short* __restrict__ WT2) {
    int b = blockIdx.x;
    if (b < NBLK) {
        int i = b * 256 + threadIdx.x;
        if (i < N_NODES) cnt[i] = 0;
    } else {
        int bb = b - NBLK;
        int k = bb & 255;
        const float* W = (bb >> 8) ? W2f : W1f;
        unsigned short* WT = (bb >> 8) ? WT2 : WT1;
        WT[threadIdx.x * CH + k] = f2b(W[k * CH + threadIdx.x]);
    }
}

__global__ void count_deg(const int* __restrict__ dst, int* __restrict__ cnt) {
    int e = blockIdx.x * blockDim.x + threadIdx.x;
    if (e < N_EDGES) atomicAdd(&cnt[dst[e]], 1);
}

__global__ __launch_bounds__(256) void block_reduce(const int* __restrict__ cnt,
                                                    int* __restrict__ bsum,
                                                    float* __restrict__ dinv) {
    __shared__ int s[256];
    int tid = threadIdx.x;
    int i = blockIdx.x * 256 + tid;
    int v = (i < N_NODES) ? cnt[i] : 0;
    if (i < N_NODES) dinv[i] = rsqrtf(1.0f + (float)v);
    s[tid] = v;
    __syncthreads();
    #pragma unroll
    for (int off = 128; off > 0; off >>= 1) {
        if (tid < off) s[tid] += s[tid + off];
        __syncthreads();
    }
    if (tid == 0) bsum[blockIdx.x] = s[0];
}

// per-block scan + redundant in-block scan of the <=256 block sums
__global__ __launch_bounds__(256) void block_scan(const int* __restrict__ cnt,
                                                  const int* __restrict__ bsum,
                                                  int* __restrict__ rowptr,
                                                  int* __restrict__ cursor) {
    __shared__ int s[256], sb[256];
    int tid = threadIdx.x;
    int i = blockIdx.x * 256 + tid;
    int bv = (tid < NBLK) ? bsum[tid] : 0;
    sb[tid] = bv;
    __syncthreads();
    #pragma unroll
    for (int off = 1; off < 256; off <<= 1) {
        int t = (tid >= off) ? sb[tid - off] : 0;
        __syncthreads();
        sb[tid] += t;
        __syncthreads();
    }
    const int base = (blockIdx.x == 0) ? 0 : sb[blockIdx.x - 1];
    int v = (i < N_NODES) ? cnt[i] : 0;
    s[tid] = v;
    __syncthreads();
    #pragma unroll
    for (int off = 1; off < 256; off <<= 1) {
        int t = (tid >= off) ? s[tid - off] : 0;
        __syncthreads();
        s[tid] += t;
        __syncthreads();
    }
    if (i < N_NODES) {
        int val = base + s[tid] - v;
        rowptr[i] = val;
        cursor[i] = val;
        if (i == N_NODES - 1) rowptr[N_NODES] = base + s[tid];
    }
}

__global__ void fill_csr(const int* __restrict__ src, const int* __restrict__ dst,
                         int* __restrict__ cursor, int* __restrict__ col) {
    int e = blockIdx.x * blockDim.x + threadIdx.x;
    if (e < N_EDGES) {
        int d = dst[e];
        int p = atomicAdd(&cursor[d], 1);
        col[p] = src[e];
    }
}

// ---------------- MFMA GEMMs: no LDS, 32x32 WAVE TILES for max occupancy.
// Total waves = 50000*256/1024 = 12.5K (full machine) vs 3.1K at 64x64 tiles.
// Latency-bound regime: delivered BW ~ resident waves (agg kernel proves 3.7TB/s at 70% occ).
// Block = 4 waves covering 64x64 (2x2 of 32x32); grid (782, 4).

// layer 2: A bf16
__global__ __launch_bounds__(256, 6) void gemm_bf16(const unsigned short* __restrict__ A,
                                                    const unsigned short* __restrict__ BT,
                                                    const float* __restrict__ dinv,
                                                    unsigned short* __restrict__ out) {
    const int row0 = blockIdx.x * 64;
    const int col0 = blockIdx.y * 64;
    const int tid = threadIdx.x;
    const int w = tid >> 6, l = tid & 63;
    const int wr = w >> 1, wc = w & 1;
    const int lr = l & 15, lg = l >> 4;
    const int arow0 = row0 + wr * 32;
    const int bcol0 = col0 + wc * 32;

    int arow[2];
    #pragma unroll
    for (int fm = 0; fm < 2; fm++) {
        int r = arow0 + fm * 16 + lr;
        arow[fm] = (r < N_NODES) ? r : (N_NODES - 1);   // clamped; tail writes guarded
    }

    f32x4 acc[2][2] = {};
    #pragma unroll
    for (int ks = 0; ks < 8; ks++) {
        bf16x8 af[2], bfr[2];
        #pragma unroll
        for (int fm = 0; fm < 2; fm++)
            af[fm] = *(const bf16x8*)&A[(size_t)arow[fm] * CH + ks * 32 + lg * 8];
        #pragma unroll
        for (int fn = 0; fn < 2; fn++)
            bfr[fn] = *(const bf16x8*)&BT[(size_t)(bcol0 + fn * 16 + lr) * CH + ks * 32 + lg * 8];
        #pragma unroll
        for (int fm = 0; fm < 2; fm++)
            #pragma unroll
            for (int fn = 0; fn < 2; fn++)
                acc[fm][fn] = __builtin_amdgcn_mfma_f32_16x16x32_bf16(af[fm], bfr[fn], acc[fm][fn], 0, 0, 0);
    }

    #pragma unroll
    for (int fm = 0; fm < 2; fm++) {
        #pragma unroll
        for (int r = 0; r < 4; r++) {
            int grow = arow0 + fm * 16 + lg * 4 + r;
            if (grow < N_NODES) {
                float s = dinv[grow];
                #pragma unroll
                for (int fn = 0; fn < 2; fn++) {
                    int gcol = bcol0 + fn * 16 + lr;
                    out[(size_t)grow * CH + gcol] = f2b(acc[fm][fn][r] * s);
                }
            }
        }
    }
}

// layer 1: A f32 (harness x) — direct loads + in-register f32->bf16 convert
__global__ __launch_bounds__(256, 5) void gemm_f32a(const float* __restrict__ Af,
                                                    const unsigned short* __restrict__ BT,
                                                    const float* __restrict__ dinv,
                                                    unsigned short* __restrict__ out) {
    const int row0 = blockIdx.x * 64;
    const int col0 = blockIdx.y * 64;
    const int tid = threadIdx.x;
    const int w = tid >> 6, l = tid & 63;
    const int wr = w >> 1, wc = w & 1;
    const int lr = l & 15, lg = l >> 4;
    const int arow0 = row0 + wr * 32;
    const int bcol0 = col0 + wc * 32;

    int arow[2];
    #pragma unroll
    for (int fm = 0; fm < 2; fm++) {
        int r = arow0 + fm * 16 + lr;
        arow[fm] = (r < N_NODES) ? r : (N_NODES - 1);
    }

    f32x4 acc[2][2] = {};
    #pragma unroll
    for (int ks = 0; ks < 8; ks++) {
        bf16x8 af[2], bfr[2];
        #pragma unroll
        for (int fm = 0; fm < 2; fm++) {
            const float* ap = &Af[(size_t)arow[fm] * CH + ks * 32 + lg * 8];
            float4 v0 = *(const float4*)ap;
            float4 v1 = *(const float4*)(ap + 4);
            uint4 ua = make_uint4(pack2(v0.x, v0.y), pack2(v0.z, v0.w),
                                  pack2(v1.x, v1.y), pack2(v1.z, v1.w));
            af[fm] = *(bf16x8*)&ua;
        }
        #pragma unroll
        for (int fn = 0; fn < 2; fn++)
            bfr[fn] = *(const bf16x8*)&BT[(size_t)(bcol0 + fn * 16 + lr) * CH + ks * 32 + lg * 8];
        #pragma unroll
        for (int fm = 0; fm < 2; fm++)
            #pragma unroll
            for (int fn = 0; fn < 2; fn++)
                acc[fm][fn] = __builtin_amdgcn_mfma_f32_16x16x32_bf16(af[fm], bfr[fn], acc[fm][fn], 0, 0, 0);
    }

    #pragma unroll
    for (int fm = 0; fm < 2; fm++) {
        #pragma unroll
        for (int r = 0; r < 4; r++) {
            int grow = arow0 + fm * 16 + lg * 4 + r;
            if (grow < N_NODES) {
                float s = dinv[grow];
                #pragma unroll
                for (int fn = 0; fn < 2; fn++) {
                    int gcol = bcol0 + fn * 16 + lr;
                    out[(size_t)grow * CH + gcol] = f2b(acc[fm][fn][r] * s);
                }
            }
        }
    }
}

// ---------------- aggregation + LN + LeakyReLU, one WAVE per node (r5/r9 verified 58us form)
__global__ __launch_bounds__(256) void agg_ln_bf16(const unsigned short* __restrict__ h,
                                                   const int* __restrict__ rowptr,
                                                   const int* __restrict__ col,
                                                   const float* __restrict__ dinv,
                                                   const float* __restrict__ bias,
                                                   const float* __restrict__ lnw,
                                                   const float* __restrict__ lnb,
                                                   unsigned short* __restrict__ out) {
    const int w = threadIdx.x >> 6, lane = threadIdx.x & 63;
    const int d = blockIdx.x * 4 + w;
    if (d >= N_NODES) return;   // wave-uniform exit
    const int c4 = lane * 4;
    const uint2* __restrict__ h2 = (const uint2*)h;   // h2[node*64 + lane] = 4 channels

    f32x2 acc01, acc23;
    {
        uint2 u = h2[(unsigned)(d * 64 + lane)];      // self loop
        acc01 = b2f2(u.x); acc23 = b2f2(u.y);
    }

    const int e0 = rowptr[d], e1 = rowptr[d + 1];
    for (int base = e0; base < e1; base += 64) {
        int nch = e1 - base; if (nch > 64) nch = 64;
        int cidx = (lane < nch) ? col[base + lane] : 0;
        int j = 0;
        for (; j + 8 <= nch; j += 8) {
            int s0 = __shfl(cidx, j),     s1 = __shfl(cidx, j + 1);
            int s2 = __shfl(cidx, j + 2), s3 = __shfl(cidx, j + 3);
            int s4 = __shfl(cidx, j + 4), s5 = __shfl(cidx, j + 5);
            int s6 = __shfl(cidx, j + 6), s7 = __shfl(cidx, j + 7);
            uint2 u0 = h2[(unsigned)(s0 * 64 + lane)];
            uint2 u1 = h2[(unsigned)(s1 * 64 + lane)];
            uint2 u2 = h2[(unsigned)(s2 * 64 + lane)];
            uint2 u3 = h2[(unsigned)(s3 * 64 + lane)];
            uint2 u4 = h2[(unsigned)(s4 * 64 + lane)];
            uint2 u5 = h2[(unsigned)(s5 * 64 + lane)];
            uint2 u6 = h2[(unsigned)(s6 * 64 + lane)];
            uint2 u7 = h2[(unsigned)(s7 * 64 + lane)];
            acc01 += b2f2(u0.x) + b2f2(u1.x) + b2f2(u2.x) + b2f2(u3.x);
            acc23 += b2f2(u0.y) + b2f2(u1.y) + b2f2(u2.y) + b2f2(u3.y);
            acc01 += b2f2(u4.x) + b2f2(u5.x) + b2f2(u6.x) + b2f2(u7.x);
            acc23 += b2f2(u4.y) + b2f2(u5.y) + b2f2(u6.y) + b2f2(u7.y);
        }
        for (; j + 4 <= nch; j += 4) {
            int s0 = __shfl(cidx, j),     s1 = __shfl(cidx, j + 1);
            int s2 = __shfl(cidx, j + 2), s3 = __shfl(cidx, j + 3);
            uint2 u0 = h2[(unsigned)(s0 * 64 + lane)];
            uint2 u1 = h2[(unsigned)(s1 * 64 + lane)];
            uint2 u2 = h2[(unsigned)(s2 * 64 + lane)];
            uint2 u3 = h2[(unsigned)(s3 * 64 + lane)];
            acc01 += b2f2(u0.x) + b2f2(u1.x) + b2f2(u2.x) + b2f2(u3.x);
            acc23 += b2f2(u0.y) + b2f2(u1.y) + b2f2(u2.y) + b2f2(u3.y);
        }
        for (; j < nch; j++) {
            int s = __shfl(cidx, j);
            uint2 u = h2[(unsigned)(s * 64 + lane)];
            acc01 += b2f2(u.x); acc23 += b2f2(u.y);
        }
    }
    float a0 = acc01.x, a1 = acc01.y, a2 = acc23.x, a3 = acc23.y;
    const float di = dinv[d];
    float4 bb = *(const float4*)&bias[c4];
    a0 = a0 * di + bb.x; a1 = a1 * di + bb.y; a2 = a2 * di + bb.z; a3 = a3 * di + bb.w;

    float s1 = a0 + a1 + a2 + a3;
    float s2 = a0 * a0 + a1 * a1 + a2 * a2 + a3 * a3;
    #pragma unroll
    for (int off = 32; off > 0; off >>= 1) {
        s1 += __shfl_xor(s1, off);
        s2 += __shfl_xor(s2, off);
    }
    const float mu = s1 * (1.0f / CH);
    const float rstd = rsqrtf(s2 * (1.0f / CH) - mu * mu + LN_EPS);
    float4 wv = *(const float4*)&lnw[c4];
    float4 bv = *(const float4*)&lnb[c4];
    float y0 = (a0 - mu) * rstd * wv.x + bv.x;
    float y1 = (a1 - mu) * rstd * wv.y + bv.y;
    float y2 = (a2 - mu) * rstd * wv.z + bv.z;
    float y3 = (a3 - mu) * rstd * wv.w + bv.w;
    y0 = fmaxf(y0, LEAKY * y0);
    y1 = fmaxf(y1, LEAKY * y1);
    y2 = fmaxf(y2, LEAKY * y2);
    y3 = fmaxf(y3, LEAKY * y3);
    *(ushort4*)&out[(size_t)d * CH + c4] = make_ushort4(f2b(y0), f2b(y1), f2b(y2), f2b(y3));
}

// 4 waves per graph, node range split across waves, LDS cross-wave reduce
__global__ __launch_bounds__(256) void pool_mean_bf16(const unsigned short* __restrict__ feat,
                                                      const int* __restrict__ batch,
                                                      float* __restrict__ out) {
    const int g = blockIdx.x;
    const int w = threadIdx.x >> 6, lane = threadIdx.x & 63;
    int lo = 0, hi = N_NODES;
    while (lo < hi) { int mid = (lo + hi) >> 1; if (batch[mid] < g) lo = mid + 1; else hi = mid; }
    const int start = lo;
    hi = N_NODES;
    while (lo < hi) { int mid = (lo + hi) >> 1; if (batch[mid] < g + 1) lo = mid + 1; else hi = mid; }
    const int end = lo;

    float a0 = 0.f, a1 = 0.f, a2 = 0.f, a3 = 0.f;
    for (int n = start + w; n < end; n += 4) {
        ushort4 u = *(const ushort4*)&feat[(size_t)n * CH + lane * 4];
        a0 += b2f(u.x); a1 += b2f(u.y); a2 += b2f(u.z); a3 += b2f(u.w);
    }
    __shared__ float4 red[4][64];
    red[w][lane] = make_float4(a0, a1, a2, a3);
    __syncthreads();
    if (w == 0) {
        float4 t0 = red[0][lane], t1 = red[1][lane], t2 = red[2][lane], t3 = red[3][lane];
        const float inv = (end > start) ? 1.0f / (float)(end - start) : 0.0f;
        float4 o = make_float4((t0.x + t1.x + t2.x + t3.x) * inv,
                               (t0.y + t1.y + t2.y + t3.y) * inv,
                               (t0.z + t1.z + t2.z + t3.z) * inv,
                               (t0.w + t1.w + t2.w + t3.w) * inv);
        *(float4*)&out[(size_t)g * CH + lane * 4] = o;
    }
}

static inline size_t align256(size_t x) { return (x + 255) & ~(size_t)255; }

extern "C" void kernel_launch(void* const* d_in, const int* in_sizes, int n_in,
                              void* d_out, int out_size, void* d_ws, size_t ws_size,
                              hipStream_t stream) {
    const float* x    = (const float*)d_in[0];
    const int*   edge = (const int*)d_in[1];
    const int*   batch= (const int*)d_in[2];
    const float* W1   = (const float*)d_in[3];
    const float* b1   = (const float*)d_in[4];
    const float* ln1w = (const float*)d_in[5];
    const float* ln1b = (const float*)d_in[6];
    const float* W2   = (const float*)d_in[7];
    const float* b2   = (const float*)d_in[8];
    const float* ln2w = (const float*)d_in[9];
    const float* ln2b = (const float*)d_in[10];

    const int* src = edge;
    const int* dst = edge + N_EDGES;

    char* p = (char*)d_ws;
    int* cnt    = (int*)p;  p += align256(N_NODES * 4);
    int* cursor = (int*)p;  p += align256(N_NODES * 4);
    int* rowptr = (int*)p;  p += align256((N_NODES + 1) * 4);
    int* bsum   = (int*)p;  p += align256(NBLK * 4);
    float* dinv = (float*)p; p += align256(N_NODES * 4);
    int* col    = (int*)p;  p += align256(N_EDGES * 4);
    unsigned short* wt1 = (unsigned short*)p; p += align256(CH * CH * 2);
    unsigned short* wt2 = (unsigned short*)p; p += align256(CH * CH * 2);
    unsigned short* bufA = (unsigned short*)p; p += align256((size_t)N_NODES * CH * 2);  // h
    unsigned short* bufB = (unsigned short*)p; p += align256((size_t)N_NODES * CH * 2);  // y
    p += 65536;  // safety pad

    prep<<<NBLK + 2 * CH, 256, 0, stream>>>(cnt, W1, W2, wt1, wt2);
    count_deg<<<(N_EDGES + 255) / 256, 256, 0, stream>>>(dst, cnt);
    block_reduce<<<NBLK, 256, 0, stream>>>(cnt, bsum, dinv);
    block_scan<<<NBLK, 256, 0, stream>>>(cnt, bsum, rowptr, cursor);
    fill_csr<<<(N_EDGES + 255) / 256, 256, 0, stream>>>(src, dst, cursor, col);

    dim3 ggrid((N_NODES + 63) / 64, 4);   // 782 x 4 = 3128 blocks, 12512 waves
    gemm_f32a<<<ggrid, 256, 0, stream>>>(x, wt1, dinv, bufA);
    agg_ln_bf16<<<(N_NODES + 3) / 4, 256, 0, stream>>>(bufA, rowptr, col, dinv, b1, ln1w, ln1b, bufB);
    gemm_bf16<<<ggrid, 256, 0, stream>>>(bufB, wt2, dinv, bufA);
    agg_ln_bf16<<<(N_NODES + 3) / 4, 256, 0, stream>>>(bufA, rowptr, col, dinv, b2, ln2w, ln2b, bufB);
    pool_mean_bf16<<<NUM_GRAPHS, 256, 0, stream>>>(bufB, batch, (float*)d_out);
}

// Round 17
// 286.323 us; speedup vs baseline: 1.2494x; 1.2494x over previous
//
#include <hip/hip_runtime.h>

#define N_NODES 50000
#define N_EDGES 800000
#define CH 256
#define NUM_GRAPHS 512
#define LEAKY 0.01f
#define LN_EPS 1e-5f
#define NBLK ((N_NODES + 255) / 256)   // 196

typedef __attribute__((ext_vector_type(4))) float f32x4;
typedef __attribute__((ext_vector_type(2))) float f32x2;
typedef __attribute__((ext_vector_type(8))) short bf16x8;

__device__ __forceinline__ float b2f(unsigned short u) {
    union { unsigned int i; float f; } x; x.i = ((unsigned int)u) << 16; return x.f;
}
__device__ __forceinline__ unsigned short f2b(float f) {  // round-to-nearest-even
    union { float f; unsigned int i; } x; x.f = f;
    unsigned int r = x.i + 0x7fffu + ((x.i >> 16) & 1u);
    return (unsigned short)(r >> 16);
}
__device__ __forceinline__ f32x2 b2f2(unsigned int u) {
    union { unsigned int i; float f; } lo, hi;
    lo.i = u << 16; hi.i = u & 0xffff0000u;
    f32x2 r; r.x = lo.f; r.y = hi.f; return r;
}
__device__ __forceinline__ unsigned int pack2(float a, float b) {
    return (unsigned int)f2b(a) | ((unsigned int)f2b(b) << 16);
}
// async global->LDS, 16B per lane; LDS dest is wave-uniform base + lane*16
__device__ __forceinline__ void gload16(const void* g, void* l) {
    __builtin_amdgcn_global_load_lds((const __attribute__((address_space(1))) unsigned int*)g,
                                     (__attribute__((address_space(3))) unsigned int*)l, 16, 0, 0);
}

// merged: zero cnt (blocks [0,NBLK)) + W1/W2 transpose-cast (blocks [NBLK, NBLK+512))
__global__ void prep(int* __restrict__ cnt,
                     const float* __restrict__ W1f, const float* __restrict__ W2f,
                     unsigned short* __restrict__ WT1, unsigned short* __restrict__ WT2) {
    int b = blockIdx.x;
    if (b < NBLK) {
        int i = b * 256 + threadIdx.x;
        if (i < N_NODES) cnt[i] = 0;
    } else {
        int bb = b - NBLK;
        int k = bb & 255;
        const float* W = (bb >> 8) ? W2f : W1f;
        unsigned short* WT = (bb >> 8) ? WT2 : WT1;
        WT[threadIdx.x * CH + k] = f2b(W[k * CH + threadIdx.x]);
    }
}

__global__ void count_deg(const int* __restrict__ dst, int* __restrict__ cnt) {
    int e = blockIdx.x * blockDim.x + threadIdx.x;
    if (e < N_EDGES) atomicAdd(&cnt[dst[e]], 1);
}

__global__ __launch_bounds__(256) void block_reduce(const int* __restrict__ cnt,
                                                    int* __restrict__ bsum,
                                                    float* __restrict__ dinv) {
    __shared__ int s[256];
    int tid = threadIdx.x;
    int i = blockIdx.x * 256 + tid;
    int v = (i < N_NODES) ? cnt[i] : 0;
    if (i < N_NODES) dinv[i] = rsqrtf(1.0f + (float)v);
    s[tid] = v;
    __syncthreads();
    #pragma unroll
    for (int off = 128; off > 0; off >>= 1) {
        if (tid < off) s[tid] += s[tid + off];
        __syncthreads();
    }
    if (tid == 0) bsum[blockIdx.x] = s[0];
}

// per-block scan + redundant in-block scan of the <=256 block sums (scan_bsums folded in)
__global__ __launch_bounds__(256) void block_scan(const int* __restrict__ cnt,
                                                  const int* __restrict__ bsum,
                                                  int* __restrict__ rowptr,
                                                  int* __restrict__ cursor) {
    __shared__ int s[256], sb[256];
    int tid = threadIdx.x;
    int i = blockIdx.x * 256 + tid;
    int bv = (tid < NBLK) ? bsum[tid] : 0;
    sb[tid] = bv;
    __syncthreads();
    #pragma unroll
    for (int off = 1; off < 256; off <<= 1) {
        int t = (tid >= off) ? sb[tid - off] : 0;
        __syncthreads();
        sb[tid] += t;
        __syncthreads();
    }
    const int base = (blockIdx.x == 0) ? 0 : sb[blockIdx.x - 1];
    int v = (i < N_NODES) ? cnt[i] : 0;
    s[tid] = v;
    __syncthreads();
    #pragma unroll
    for (int off = 1; off < 256; off <<= 1) {
        int t = (tid >= off) ? s[tid - off] : 0;
        __syncthreads();
        s[tid] += t;
        __syncthreads();
    }
    if (i < N_NODES) {
        int val = base + s[tid] - v;
        rowptr[i] = val;
        cursor[i] = val;
        if (i == N_NODES - 1) rowptr[N_NODES] = base + s[tid];
    }
}

__global__ void fill_csr(const int* __restrict__ src, const int* __restrict__ dst,
                         int* __restrict__ cursor, int* __restrict__ col) {
    int e = blockIdx.x * blockDim.x + threadIdx.x;
    if (e < N_EDGES) {
        int d = dst[e];
        int p = atomicAdd(&cursor[d], 1);
        col[p] = src[e];
    }
}

// ---------------- MFMA GEMMs (round-9 verified config: BM/BN/BK 128/128/64, grid 391x2)
#define BM 128
#define BN 128
#define BK 64
#define SWZ(row, kb) (((row) * 128 + (kb) * 16) ^ (((row) & 7) << 4))

// layer 2: A bf16 (ws buffer, padded) -> both tiles via global_load_lds (pre-swizzled source)
__global__ __launch_bounds__(256) void gemm_bf16(const unsigned short* __restrict__ A,
                                                 const unsigned short* __restrict__ BT,
                                                 const float* __restrict__ dinv,
                                                 unsigned short* __restrict__ out) {
    __shared__ unsigned short As[BM * BK];
    __shared__ unsigned short Bs[BN * BK];
    const int row0 = blockIdx.x * BM;
    const int col0 = blockIdx.y * BN;
    const int tid = threadIdx.x;
    const int w = tid >> 6, l = tid & 63;
    const int wr = w >> 1, wc = w & 1;
    const int lr = l & 15, lg = l >> 4;
    const int sr = l >> 3, kbp = l & 7;

    f32x4 acc[4][4] = {};

    for (int k0 = 0; k0 < CH; k0 += BK) {
        #pragma unroll
        for (int it = 0; it < 4; it++) {
            const int R = (w * 4 + it) * 8;
            const int r = R + sr;
            const int kb = kbp ^ (r & 7);
            gload16(&A[(size_t)(row0 + r) * CH + k0 + kb * 8], (char*)As + R * 128);
            gload16(&BT[(size_t)(col0 + r) * CH + k0 + kb * 8], (char*)Bs + R * 128);
        }
        __syncthreads();
        #pragma unroll
        for (int ks = 0; ks < 2; ks++) {
            bf16x8 af[4], bfr[4];
            #pragma unroll
            for (int fm = 0; fm < 4; fm++) {
                int r = wr * 64 + fm * 16 + lr;
                af[fm] = *(const bf16x8*)((const char*)As + SWZ(r, ks * 4 + lg));
            }
            #pragma unroll
            for (int fn = 0; fn < 4; fn++) {
                int r = wc * 64 + fn * 16 + lr;
                bfr[fn] = *(const bf16x8*)((const char*)Bs + SWZ(r, ks * 4 + lg));
            }
            #pragma unroll
            for (int fm = 0; fm < 4; fm++)
                #pragma unroll
                for (int fn = 0; fn < 4; fn++)
                    acc[fm][fn] = __builtin_amdgcn_mfma_f32_16x16x32_bf16(af[fm], bfr[fn], acc[fm][fn], 0, 0, 0);
        }
        __syncthreads();
    }
    #pragma unroll
    for (int fm = 0; fm < 4; fm++) {
        #pragma unroll
        for (int r = 0; r < 4; r++) {
            int grow = row0 + wr * 64 + fm * 16 + lg * 4 + r;
            if (grow < N_NODES) {
                float s = dinv[grow];
                #pragma unroll
                for (int fn = 0; fn < 4; fn++) {
                    int gcol = col0 + wc * 64 + fn * 16 + lr;
                    out[(size_t)grow * CH + gcol] = f2b(acc[fm][fn][r] * s);
                }
            }
        }
    }
}

// layer 1: A f32 (guarded reg staging + cvt); B via global_load_lds
__global__ __launch_bounds__(256) void gemm_f32a(const float* __restrict__ Af,
                                                 const unsigned short* __restrict__ BT,
                                                 const float* __restrict__ dinv,
                                                 unsigned short* __restrict__ out) {
    __shared__ unsigned short As[BM * BK];
    __shared__ unsigned short Bs[BN * BK];
    const int row0 = blockIdx.x * BM;
    const int col0 = blockIdx.y * BN;
    const int tid = threadIdx.x;
    const int w = tid >> 6, l = tid & 63;
    const int wr = w >> 1, wc = w & 1;
    const int lr = l & 15, lg = l >> 4;
    const int sr = l >> 3, kbp = l & 7;

    f32x4 acc[4][4] = {};

    for (int k0 = 0; k0 < CH; k0 += BK) {
        #pragma unroll
        for (int it = 0; it < 4; it++) {
            const int R = (w * 4 + it) * 8;
            const int r = R + sr;
            const int kb = kbp ^ (r & 7);
            gload16(&BT[(size_t)(col0 + r) * CH + k0 + kb * 8], (char*)Bs + R * 128);
        }
        #pragma unroll
        for (int it = 0; it < 4; it++) {
            int cidx = it * 256 + tid;
            int r = cidx >> 3, kb = cidx & 7;
            int grow = row0 + r;
            uint4 ua = make_uint4(0u, 0u, 0u, 0u);
            if (grow < N_NODES) {
                const float* ap = &Af[(size_t)grow * CH + k0 + kb * 8];
                float4 v0 = *(const float4*)ap;
                float4 v1 = *(const float4*)(ap + 4);
                ua = make_uint4(pack2(v0.x, v0.y), pack2(v0.z, v0.w),
                                pack2(v1.x, v1.y), pack2(v1.z, v1.w));
            }
            *(uint4*)((char*)As + SWZ(r, kb)) = ua;
        }
        __syncthreads();
        #pragma unroll
        for (int ks = 0; ks < 2; ks++) {
            bf16x8 af[4], bfr[4];
            #pragma unroll
            for (int fm = 0; fm < 4; fm++) {
                int r = wr * 64 + fm * 16 + lr;
                af[fm] = *(const bf16x8*)((const char*)As + SWZ(r, ks * 4 + lg));
            }
            #pragma unroll
            for (int fn = 0; fn < 4; fn++) {
                int r = wc * 64 + fn * 16 + lr;
                bfr[fn] = *(const bf16x8*)((const char*)Bs + SWZ(r, ks * 4 + lg));
            }
            #pragma unroll
            for (int fm = 0; fm < 4; fm++)
                #pragma unroll
                for (int fn = 0; fn < 4; fn++)
                    acc[fm][fn] = __builtin_amdgcn_mfma_f32_16x16x32_bf16(af[fm], bfr[fn], acc[fm][fn], 0, 0, 0);
        }
        __syncthreads();
    }
    #pragma unroll
    for (int fm = 0; fm < 4; fm++) {
        #pragma unroll
        for (int r = 0; r < 4; r++) {
            int grow = row0 + wr * 64 + fm * 16 + lg * 4 + r;
            if (grow < N_NODES) {
                float s = dinv[grow];
                #pragma unroll
                for (int fn = 0; fn < 4; fn++) {
                    int gcol = col0 + wc * 64 + fn * 16 + lr;
                    out[(size_t)grow * CH + gcol] = f2b(acc[fm][fn][r] * s);
                }
            }
        }
    }
}

// ---------------- aggregation + LN + LeakyReLU, one WAVE per node (r5/r9 verified 58us form)
__global__ __launch_bounds__(256) void agg_ln_bf16(const unsigned short* __restrict__ h,
                                                   const int* __restrict__ rowptr,
                                                   const int* __restrict__ col,
                                                   const float* __restrict__ dinv,
                                                   const float* __restrict__ bias,
                                                   const float* __restrict__ lnw,
                                                   const float* __restrict__ lnb,
                                                   unsigned short* __restrict__ out) {
    const int w = threadIdx.x >> 6, lane = threadIdx.x & 63;
    const int d = blockIdx.x * 4 + w;
    if (d >= N_NODES) return;   // wave-uniform exit
    const int c4 = lane * 4;
    const uint2* __restrict__ h2 = (const uint2*)h;   // h2[node*64 + lane] = 4 channels

    f32x2 acc01, acc23;
    {
        uint2 u = h2[(unsigned)(d * 64 + lane)];      // self loop
        acc01 = b2f2(u.x); acc23 = b2f2(u.y);
    }

    const int e0 = rowptr[d], e1 = rowptr[d + 1];
    for (int base = e0; base < e1; base += 64) {
        int nch = e1 - base; if (nch > 64) nch = 64;
        int cidx = (lane < nch) ? col[base + lane] : 0;
        int j = 0;
        for (; j + 8 <= nch; j += 8) {
            int s0 = __shfl(cidx, j),     s1 = __shfl(cidx, j + 1);
            int s2 = __shfl(cidx, j + 2), s3 = __shfl(cidx, j + 3);
            int s4 = __shfl(cidx, j + 4), s5 = __shfl(cidx, j + 5);
            int s6 = __shfl(cidx, j + 6), s7 = __shfl(cidx, j + 7);
            uint2 u0 = h2[(unsigned)(s0 * 64 + lane)];
            uint2 u1 = h2[(unsigned)(s1 * 64 + lane)];
            uint2 u2 = h2[(unsigned)(s2 * 64 + lane)];
            uint2 u3 = h2[(unsigned)(s3 * 64 + lane)];
            uint2 u4 = h2[(unsigned)(s4 * 64 + lane)];
            uint2 u5 = h2[(unsigned)(s5 * 64 + lane)];
            uint2 u6 = h2[(unsigned)(s6 * 64 + lane)];
            uint2 u7 = h2[(unsigned)(s7 * 64 + lane)];
            acc01 += b2f2(u0.x) + b2f2(u1.x) + b2f2(u2.x) + b2f2(u3.x);
            acc23 += b2f2(u0.y) + b2f2(u1.y) + b2f2(u2.y) + b2f2(u3.y);
            acc01 += b2f2(u4.x) + b2f2(u5.x) + b2f2(u6.x) + b2f2(u7.x);
            acc23 += b2f2(u4.y) + b2f2(u5.y) + b2f2(u6.y) + b2f2(u7.y);
        }
        for (; j + 4 <= nch; j += 4) {
            int s0 = __shfl(cidx, j),     s1 = __shfl(cidx, j + 1);
            int s2 = __shfl(cidx, j + 2), s3 = __shfl(cidx, j + 3);
            uint2 u0 = h2[(unsigned)(s0 * 64 + lane)];
            uint2 u1 = h2[(unsigned)(s1 * 64 + lane)];
            uint2 u2 = h2[(unsigned)(s2 * 64 + lane)];
            uint2 u3 = h2[(unsigned)(s3 * 64 + lane)];
            acc01 += b2f2(u0.x) + b2f2(u1.x) + b2f2(u2.x) + b2f2(u3.x);
            acc23 += b2f2(u0.y) + b2f2(u1.y) + b2f2(u2.y) + b2f2(u3.y);
        }
        for (; j < nch; j++) {
            int s = __shfl(cidx, j);
            uint2 u = h2[(unsigned)(s * 64 + lane)];
            acc01 += b2f2(u.x); acc23 += b2f2(u.y);
        }
    }
    float a0 = acc01.x, a1 = acc01.y, a2 = acc23.x, a3 = acc23.y;
    const float di = dinv[d];
    float4 bb = *(const float4*)&bias[c4];
    a0 = a0 * di + bb.x; a1 = a1 * di + bb.y; a2 = a2 * di + bb.z; a3 = a3 * di + bb.w;

    float s1 = a0 + a1 + a2 + a3;
    float s2 = a0 * a0 + a1 * a1 + a2 * a2 + a3 * a3;
    #pragma unroll
    for (int off = 32; off > 0; off >>= 1) {
        s1 += __shfl_xor(s1, off);
        s2 += __shfl_xor(s2, off);
    }
    const float mu = s1 * (1.0f / CH);
    const float rstd = rsqrtf(s2 * (1.0f / CH) - mu * mu + LN_EPS);
    float4 wv = *(const float4*)&lnw[c4];
    float4 bv = *(const float4*)&lnb[c4];
    float y0 = (a0 - mu) * rstd * wv.x + bv.x;
    float y1 = (a1 - mu) * rstd * wv.y + bv.y;
    float y2 = (a2 - mu) * rstd * wv.z + bv.z;
    float y3 = (a3 - mu) * rstd * wv.w + bv.w;
    y0 = fmaxf(y0, LEAKY * y0);
    y1 = fmaxf(y1, LEAKY * y1);
    y2 = fmaxf(y2, LEAKY * y2);
    y3 = fmaxf(y3, LEAKY * y3);
    *(ushort4*)&out[(size_t)d * CH + c4] = make_ushort4(f2b(y0), f2b(y1), f2b(y2), f2b(y3));
}

// 4 waves per graph, node range split across waves, LDS cross-wave reduce
__global__ __launch_bounds__(256) void pool_mean_bf16(const unsigned short* __restrict__ feat,
                                                      const int* __restrict__ batch,
                                                      float* __restrict__ out) {
    const int g = blockIdx.x;
    const int w = threadIdx.x >> 6, lane = threadIdx.x & 63;
    int lo = 0, hi = N_NODES;
    while (lo < hi) { int mid = (lo + hi) >> 1; if (batch[mid] < g) lo = mid + 1; else hi = mid; }
    const int start = lo;
    hi = N_NODES;
    while (lo < hi) { int mid = (lo + hi) >> 1; if (batch[mid] < g + 1) lo = mid + 1; else hi = mid; }
    const int end = lo;

    float a0 = 0.f, a1 = 0.f, a2 = 0.f, a3 = 0.f;
    for (int n = start + w; n < end; n += 4) {
        ushort4 u = *(const ushort4*)&feat[(size_t)n * CH + lane * 4];
        a0 += b2f(u.x); a1 += b2f(u.y); a2 += b2f(u.z); a3 += b2f(u.w);
    }
    __shared__ float4 red[4][64];
    red[w][lane] = make_float4(a0, a1, a2, a3);
    __syncthreads();
    if (w == 0) {
        float4 t0 = red[0][lane], t1 = red[1][lane], t2 = red[2][lane], t3 = red[3][lane];
        const float inv = (end > start) ? 1.0f / (float)(end - start) : 0.0f;
        float4 o = make_float4((t0.x + t1.x + t2.x + t3.x) * inv,
                               (t0.y + t1.y + t2.y + t3.y) * inv,
                               (t0.z + t1.z + t2.z + t3.z) * inv,
                               (t0.w + t1.w + t2.w + t3.w) * inv);
        *(float4*)&out[(size_t)g * CH + lane * 4] = o;
    }
}

static inline size_t align256(size_t x) { return (x + 255) & ~(size_t)255; }

extern "C" void kernel_launch(void* const* d_in, const int* in_sizes, int n_in,
                              void* d_out, int out_size, void* d_ws, size_t ws_size,
                              hipStream_t stream) {
    const float* x    = (const float*)d_in[0];
    const int*   edge = (const int*)d_in[1];
    const int*   batch= (const int*)d_in[2];
    const float* W1   = (const float*)d_in[3];
    const float* b1   = (const float*)d_in[4];
    const float* ln1w = (const float*)d_in[5];
    const float* ln1b = (const float*)d_in[6];
    const float* W2   = (const float*)d_in[7];
    const float* b2   = (const float*)d_in[8];
    const float* ln2w = (const float*)d_in[9];
    const float* ln2b = (const float*)d_in[10];

    const int* src = edge;
    const int* dst = edge + N_EDGES;

    char* p = (char*)d_ws;
    int* cnt    = (int*)p;  p += align256(N_NODES * 4);
    int* cursor = (int*)p;  p += align256(N_NODES * 4);
    int* rowptr = (int*)p;  p += align256((N_NODES + 1) * 4);
    int* bsum   = (int*)p;  p += align256(NBLK * 4);
    float* dinv = (float*)p; p += align256(N_NODES * 4);
    int* col    = (int*)p;  p += align256(N_EDGES * 4);
    unsigned short* wt1 = (unsigned short*)p; p += align256(CH * CH * 2);
    unsigned short* wt2 = (unsigned short*)p; p += align256(CH * CH * 2);
    unsigned short* bufA = (unsigned short*)p; p += align256((size_t)N_NODES * CH * 2);  // h
    unsigned short* bufB = (unsigned short*)p; p += align256((size_t)N_NODES * CH * 2);  // y
    p += 65536;  // OOB-read pad for gemm_bf16's unguarded global_load_lds tail rows

    prep<<<NBLK + 2 * CH, 256, 0, stream>>>(cnt, W1, W2, wt1, wt2);
    count_deg<<<(N_EDGES + 255) / 256, 256, 0, stream>>>(dst, cnt);
    block_reduce<<<NBLK, 256, 0, stream>>>(cnt, bsum, dinv);
    block_scan<<<NBLK, 256, 0, stream>>>(cnt, bsum, rowptr, cursor);
    fill_csr<<<(N_EDGES + 255) / 256, 256, 0, stream>>>(src, dst, cursor, col);

    dim3 ggrid((N_NODES + BM - 1) / BM, CH / BN);   // 391 x 2
    gemm_f32a<<<ggrid, 256, 0, stream>>>(x, wt1, dinv, bufA);
    agg_ln_bf16<<<(N_NODES + 3) / 4, 256, 0, stream>>>(bufA, rowptr, col, dinv, b1, ln1w, ln1b, bufB);
    gemm_bf16<<<ggrid, 256, 0, stream>>>(bufB, wt2, dinv, bufA);
    agg_ln_bf16<<<(N_NODES + 3) / 4, 256, 0, stream>>>(bufA, rowptr, col, dinv, b2, ln2w, ln2b, bufB);
    pool_mean_bf16<<<NUM_GRAPHS, 256, 0, stream>>>(bufB, batch, (float*)d_out);
}